// Round 7
// baseline (248.438 us; speedup 1.0000x reference)
//
#include <hip/hip_runtime.h>
#include <hip/hip_bf16.h>

#define BATCH 4096
#define TSTEPS 256
#define NF 5
#define H 64
#define BT 8           // batch tile per block (sparse rows 0,1,4,5,8,9,12,13)
#define LDH 136        // hreg row stride in ushorts
#define NBLK (BATCH / BT)   // 512 blocks -> 2 blocks/CU -> 2 waves/SIMD

typedef __attribute__((ext_vector_type(8))) short bf16x8;
typedef __attribute__((ext_vector_type(4))) float f32x4;

#define LOG2E 1.4426950408889634f
#define TWOLOG2E 2.8853900817779268f

__device__ __forceinline__ ushort f2bf(float f) {
    union { float f; unsigned u; } v; v.f = f;
    unsigned u = v.u;
    unsigned r = (u + 0x7FFFu + ((u >> 16) & 1u)) >> 16;  // RNE
    return (ushort)r;
}
__device__ __forceinline__ float bf2f(ushort s) {
    union { unsigned u; float f; } v; v.u = ((unsigned)s) << 16;
    return v.f;
}
// pack two fp32 -> two bf16 (RNE) in one instruction
__device__ __forceinline__ unsigned pk_bf16(float lo, float hi) {
    unsigned pk;
    asm("v_cvt_pk_bf16_f32 %0, %1, %2" : "=v"(pk) : "v"(lo), "v"(hi));
    return pk;
}

__global__ __launch_bounds__(256, 2)
void lstm2_kernel(const float* __restrict__ x,
                  const float* __restrict__ Wih0, const float* __restrict__ Whh0,
                  const float* __restrict__ bih0, const float* __restrict__ bhh0,
                  const float* __restrict__ Wih1, const float* __restrict__ Whh1,
                  const float* __restrict__ bih1, const float* __restrict__ bhh1,
                  const float* __restrict__ Wfc, const float* __restrict__ bfc,
                  float* __restrict__ out)
{
    __shared__ union {
        ushort xs[TSTEPS * BT * 8];   // bf16 x [t][b][8]; cols 5,6 = 1.0 (bias), 7 = 0
        float  hfin[BT * H];          // epilogue: fp32 final h1
    } uS;
    __shared__ ushort hreg[2][16 * LDH];  // dbuf state; cols 0..63 h0, 64..127 h1

    const int tid = threadIdx.x;
    const int w   = tid >> 6;    // wave 0..3
    const int l   = tid & 63;
    const int g   = l >> 4;      // k-group / D-row group
    const int lr  = l & 15;     // A row / B,D col index
    const int bb  = blockIdx.x * BT;

    // ---- stage x tile into LDS as bf16; pad cols 5,6 = 1.0 (bias cols) ----
    {
        const int b  = tid & 7;
        const int t0 = tid >> 3;
        const ushort one = f2bf(1.0f);
        for (int tt = t0; tt < TSTEPS; tt += 32) {
            const float* xp = x + ((size_t)(bb + b) * TSTEPS + tt) * NF;
            bf16x8 v;
            v[0] = (short)f2bf(xp[0]); v[1] = (short)f2bf(xp[1]);
            v[2] = (short)f2bf(xp[2]); v[3] = (short)f2bf(xp[3]);
            v[4] = (short)f2bf(xp[4]); v[5] = (short)one; v[6] = (short)one; v[7] = 0;
            *(bf16x8*)&uS.xs[(tt * BT + b) * 8] = v;
        }
    }
    for (int i = tid; i < 2 * 16 * LDH; i += 256) hreg[0][i] = 0;

    // ---- weight fragments resident in VGPRs, gate-scaled for fused EW ----
    // gates i,f,o scaled +log2e (e=2^x̃=e^x); gate g scaled +2log2e (E=e^{2x}).
    // wave w covers unit u = 16w+lr; gate gi at col n = 64*gi + u.
    // k-map (A and B): chunk c, group g, elem j -> k = 32c + 8g + j.
    const int u = 16 * w + lr;
    bf16x8 w0f[4][3], w1f[4][4];
    f32x4 b1acc[4];                     // persistent L1-bias accumulator C-operands
    #pragma unroll
    for (int gi = 0; gi < 4; ++gi) {
        const float sc = (gi == 2) ? TWOLOG2E : LOG2E;
        const int n = 64 * gi + u;
        const float b0 = (bih0[n] + bhh0[n]) * sc;
        const float b1 = (bih1[n] + bhh1[n]) * sc;
        { f32x4 a = {b1, b1, b1, b1}; b1acc[gi] = a; }
        #pragma unroll
        for (int c = 0; c < 2; ++c) {                  // layer0 recurrent
            const float* p = Whh0 + n * H + 32 * c + 8 * g;
            bf16x8 v;
            #pragma unroll
            for (int j = 0; j < 8; ++j) v[j] = (short)f2bf(p[j] * sc);
            w0f[gi][c] = v;
        }
        {   // layer0 x-chunk: cols 0..4 Wih0 scaled; col5 bias_hi, col6 bias_lo
            const ushort bhi = f2bf(b0);
            const ushort blo = f2bf(b0 - bf2f(bhi));
            bf16x8 v;
            #pragma unroll
            for (int j = 0; j < 8; ++j) {
                int kk = 8 * g + j;
                ushort val = 0;
                if (kk < NF) val = f2bf(Wih0[n * NF + kk] * sc);
                else if (kk == 5) val = bhi;
                else if (kk == 6) val = blo;
                v[j] = (short)val;
            }
            w0f[gi][2] = v;
        }
        #pragma unroll
        for (int c = 0; c < 4; ++c) {                  // layer1: [Wih1 | Whh1]
            const float* p = (c < 2) ? (Wih1 + n * H + 32 * c + 8 * g)
                                     : (Whh1 + n * H + 32 * (c - 2) + 8 * g);
            bf16x8 v;
            #pragma unroll
            for (int j = 0; j < 8; ++j) v[j] = (short)f2bf(p[j] * sc);
            w1f[gi][c] = v;
        }
    }

    // fused LSTM cell: 5 exp2 + 2 rcp per cell (was 10 trans).
    //   c' = [e_f (e_i+1)(E_g+1) c + (e_f+1) e_i (E_g-1)] / [(e_f+1)(e_i+1)(E_g+1)]
    //   h  = e_o (E_c-1) / [(e_o+1)(E_c+1)],  E_c = exp2(clamp(2c'·log2e, ±15))
    auto cellfuse = [&](const f32x4* acc, int r, float& cst) -> float {
        float ei = __builtin_amdgcn_exp2f(acc[0][r]);
        float ef = __builtin_amdgcn_exp2f(acc[1][r]);
        float Eg = __builtin_amdgcn_exp2f(acc[2][r]);
        float eo = __builtin_amdgcn_exp2f(acc[3][r]);
        float a1 = ei + 1.0f, a2 = ef + 1.0f, a3 = Eg + 1.0f, a4 = Eg - 1.0f;
        float P  = a1 * a3;
        float t1 = ef * cst;
        float t3 = (a2 * ei) * a4;
        float num = fmaf(t1, P, t3);
        float R  = __builtin_amdgcn_rcpf(P * a2);
        float cn = num * R;
        cst = cn;
        float ct = __builtin_amdgcn_fmed3f(cn * TWOLOG2E, -15.0f, 15.0f);
        float Ec = __builtin_amdgcn_exp2f(ct);
        return (eo * (Ec - 1.0f)) * __builtin_amdgcn_rcpf((eo + 1.0f) * (Ec + 1.0f));
    };

    // lane group g owns batches {2g, 2g+1} at sparse rows 4g+{0,1}
    float c0[2] = {0, 0}, c1[2] = {0, 0};
    float h1fin[2] = {0, 0};
    const bool xlane = (g == 0) && ((lr & 2) == 0);
    const int  bx    = ((lr >> 2) << 1) | (lr & 1);    // batch at row lr

    __syncthreads();

    const int arow = lr * LDH;
    const f32x4 kZ = {0, 0, 0, 0};

    // Pipelined: iteration t = layer0 step t (h0[t-1], x[t]) + layer1 step t-1.
    // Double-buffered hreg -> ONE barrier per iteration.
    auto body = [&](int t, const ushort* __restrict__ rb, ushort* __restrict__ wb) {
        const bool do0 = (t < TSTEPS);
        const bool do1 = (t >= 1);

        bf16x8 a00 = *(const bf16x8*)&rb[arow + 8 * g];        // h0 chunk 0
        bf16x8 a01 = *(const bf16x8*)&rb[arow + 32 + 8 * g];   // h0 chunk 1
        bf16x8 a12, a13;
        if (do1) {
            a12 = *(const bf16x8*)&rb[arow + 64 + 8 * g];      // h1 chunk 0
            a13 = *(const bf16x8*)&rb[arow + 96 + 8 * g];      // h1 chunk 1
        }
        bf16x8 ax = {0, 0, 0, 0, 0, 0, 0, 0};
        if (do0 && xlane) ax = *(const bf16x8*)&uS.xs[(t * BT + bx) * 8];

        f32x4 acc0[4], acc1[4];
        if (do0) {
            #pragma unroll
            for (int gi = 0; gi < 4; ++gi) acc0[gi] = __builtin_amdgcn_mfma_f32_16x16x32_bf16(a00, w0f[gi][0], kZ, 0, 0, 0);
            #pragma unroll
            for (int gi = 0; gi < 4; ++gi) acc0[gi] = __builtin_amdgcn_mfma_f32_16x16x32_bf16(a01, w0f[gi][1], acc0[gi], 0, 0, 0);
            #pragma unroll
            for (int gi = 0; gi < 4; ++gi) acc0[gi] = __builtin_amdgcn_mfma_f32_16x16x32_bf16(ax,  w0f[gi][2], acc0[gi], 0, 0, 0);
        }
        if (do1) {
            #pragma unroll
            for (int gi = 0; gi < 4; ++gi) acc1[gi] = __builtin_amdgcn_mfma_f32_16x16x32_bf16(a00, w1f[gi][0], b1acc[gi], 0, 0, 0);
            #pragma unroll
            for (int gi = 0; gi < 4; ++gi) acc1[gi] = __builtin_amdgcn_mfma_f32_16x16x32_bf16(a01, w1f[gi][1], acc1[gi], 0, 0, 0);
            #pragma unroll
            for (int gi = 0; gi < 4; ++gi) acc1[gi] = __builtin_amdgcn_mfma_f32_16x16x32_bf16(a12, w1f[gi][2], acc1[gi], 0, 0, 0);
            #pragma unroll
            for (int gi = 0; gi < 4; ++gi) acc1[gi] = __builtin_amdgcn_mfma_f32_16x16x32_bf16(a13, w1f[gi][3], acc1[gi], 0, 0, 0);
        }

        if (do0) {
            float h0 = cellfuse(acc0, 0, c0[0]);
            float h1 = cellfuse(acc0, 1, c0[1]);
            unsigned pk = pk_bf16(h0, h1);
            wb[(4 * g + 0) * LDH + u] = (ushort)pk;
            wb[(4 * g + 1) * LDH + u] = (ushort)(pk >> 16);
        }
        if (do1) {
            float h0 = cellfuse(acc1, 0, c1[0]);
            float h1 = cellfuse(acc1, 1, c1[1]);
            h1fin[0] = h0; h1fin[1] = h1;
            unsigned pk = pk_bf16(h0, h1);
            wb[(4 * g + 0) * LDH + 64 + u] = (ushort)pk;
            wb[(4 * g + 1) * LDH + 64 + u] = (ushort)(pk >> 16);
        }
        __syncthreads();
    };

    #pragma unroll 1
    for (int t = 0; t < TSTEPS; t += 2) {
        body(t,     hreg[0], hreg[1]);
        body(t + 1, hreg[1], hreg[0]);
    }
    body(TSTEPS, hreg[0], hreg[1]);   // drain: layer1 step T-1

    // epilogue: FC on fp32 final h1
    #pragma unroll
    for (int r = 0; r < 2; ++r) uS.hfin[(2 * g + r) * H + u] = h1fin[r];
    __syncthreads();
    if (tid < BT * 2) {
        const int b = tid >> 1, cls = tid & 1;
        float s = bfc[cls];
        for (int k = 0; k < H; ++k) s += uS.hfin[b * H + k] * Wfc[cls * H + k];
        out[(size_t)(bb + b) * 2 + cls] = s;
    }
}

extern "C" void kernel_launch(void* const* d_in, const int* in_sizes, int n_in,
                              void* d_out, int out_size, void* d_ws, size_t ws_size,
                              hipStream_t stream) {
    const float* x    = (const float*)d_in[0];
    const float* Wih0 = (const float*)d_in[1];
    const float* Whh0 = (const float*)d_in[2];
    const float* bih0 = (const float*)d_in[3];
    const float* bhh0 = (const float*)d_in[4];
    const float* Wih1 = (const float*)d_in[5];
    const float* Whh1 = (const float*)d_in[6];
    const float* bih1 = (const float*)d_in[7];
    const float* bhh1 = (const float*)d_in[8];
    const float* Wfc  = (const float*)d_in[9];
    const float* bfc  = (const float*)d_in[10];
    float* out = (float*)d_out;

    lstm2_kernel<<<NBLK, 256, 0, stream>>>(x, Wih0, Whh0, bih0, bhh0,
                                           Wih1, Whh1, bih1, bhh1, Wfc, bfc, out);
}